// Round 2
// baseline (205.478 us; speedup 1.0000x reference)
//
#include <hip/hip_runtime.h>
#include <cstdint>
#include <cstddef>

// ---------------------------------------------------------------------------
// RetentionLayer: x->(QKVG proj + RoPE/SiLU) -> causal decay retention ->
// GroupNorm(64)*gate -> @ Wo^T.   B=2 S=2048 D=1024 H=16 Dh=64.
// GEMM-shaped work in bf16 MFMA (16x16x32), f32 accum. OUTPUT IS F32.
// ---------------------------------------------------------------------------

typedef __attribute__((ext_vector_type(4))) float  f32x4;
typedef __attribute__((ext_vector_type(8))) short  bf16x8;

#define S_LEN   2048
#define NHEADS  16
#define DMODEL  1024
#define MROWS   4096   // B*S

__device__ __forceinline__ unsigned short f2bf(float f) {
    unsigned u = __float_as_uint(f);
    u += 0x7fffu + ((u >> 16) & 1u);   // RNE
    return (unsigned short)(u >> 16);
}

// ---------------------------------------------------------------------------
// f32 -> bf16 convert: x (4096x1024) then Wq,Wk,Wv,Wg,Wo (1024x1024 each)
// ---------------------------------------------------------------------------
__global__ void convert_kernel(const float* __restrict__ x,
                               const float* __restrict__ wq, const float* __restrict__ wk,
                               const float* __restrict__ wv, const float* __restrict__ wg,
                               const float* __restrict__ wo,
                               unsigned short* __restrict__ dst) {
    const size_t total = 4194304u + 5u * 1048576u;  // 9437184
    for (size_t i = (size_t)blockIdx.x * blockDim.x + threadIdx.x;
         i * 4 < total; i += (size_t)gridDim.x * blockDim.x) {
        size_t e = i * 4;
        const float* src; size_t off;
        if (e < 4194304u) { src = x; off = e; }
        else {
            size_t r = e - 4194304u;
            int w = (int)(r >> 20); off = r & 1048575u;
            src = (w == 0) ? wq : (w == 1) ? wk : (w == 2) ? wv : (w == 3) ? wg : wo;
        }
        f32x4 v = *(const f32x4*)(src + off);
        unsigned short o0 = f2bf(v[0]), o1 = f2bf(v[1]), o2 = f2bf(v[2]), o3 = f2bf(v[3]);
        unsigned long long pack = (unsigned long long)o0 | ((unsigned long long)o1 << 16)
                                | ((unsigned long long)o2 << 32) | ((unsigned long long)o3 << 48);
        *(unsigned long long*)(dst + e) = pack;
    }
}

// ---------------------------------------------------------------------------
// RoPE tables: cos/sin[s][j], j=0..31, inv_freq = 10000^(-j/32)
// ---------------------------------------------------------------------------
__global__ void rope_tables(float* __restrict__ cosT, float* __restrict__ sinT) {
    int i = blockIdx.x * blockDim.x + threadIdx.x;
    if (i >= S_LEN * 32) return;
    int s = i >> 5, j = i & 31;
    float inv = exp2f(-(float)j * (13.287712379549449f / 32.0f)); // log2(10000)
    float ang = (float)s * inv;
    cosT[i] = cosf(ang);
    sinT[i] = sinf(ang);
}

// ---------------------------------------------------------------------------
// GEMM: C[4096,1024] = A[4096,1024] @ W[1024,1024]^T  (both bf16, K-major rows)
// 128x128 tile, BK=64, 4 waves (2x2 of 64x64). XOR-swizzled LDS (chunk^row&7).
// mode 0: ->q_hm (+RoPE)   1: ->k_hm (+RoPE)   2: ->v_hm
// mode 3: ->gate f32 (SiLU)    4: A=a2, W=Wo -> d_out (f32!)
// head-major (hm) layout: [(b*16+h)*2048 + s]*64 + d
// ---------------------------------------------------------------------------
__launch_bounds__(256, 2)
__global__ void gemm_fused(const unsigned short* __restrict__ A_x,
                           const unsigned short* __restrict__ A_a2,
                           const unsigned short* __restrict__ Wq, const unsigned short* __restrict__ Wk,
                           const unsigned short* __restrict__ Wv, const unsigned short* __restrict__ Wg,
                           const unsigned short* __restrict__ Wo,
                           const float* __restrict__ cosT, const float* __restrict__ sinT,
                           unsigned short* __restrict__ q_hm, unsigned short* __restrict__ k_hm,
                           unsigned short* __restrict__ v_hm, float* __restrict__ gate,
                           float* __restrict__ outf,
                           int mode_base) {
    int mode = mode_base + blockIdx.z;
    const unsigned short* A = (mode == 4) ? A_a2 : A_x;
    const unsigned short* W = (mode == 0) ? Wq : (mode == 1) ? Wk :
                              (mode == 2) ? Wv : (mode == 3) ? Wg : Wo;

    __shared__ __align__(16) unsigned short Ash[128 * 64];
    __shared__ __align__(16) unsigned short Bsh[128 * 64];

    int tid = threadIdx.x;
    int lane = tid & 63, wid = tid >> 6;
    int wm = wid >> 1, wn = wid & 1;
    int m0 = blockIdx.y * 128, n0 = blockIdx.x * 128;

    f32x4 acc[4][4];
#pragma unroll
    for (int i = 0; i < 4; ++i)
#pragma unroll
        for (int j = 0; j < 4; ++j)
#pragma unroll
            for (int r = 0; r < 4; ++r) acc[i][j][r] = 0.0f;

    for (int k0 = 0; k0 < 1024; k0 += 64) {
        __syncthreads();
#pragma unroll
        for (int t = 0; t < 4; ++t) {
            int chunk = tid + t * 256;           // 1024 chunks = 128 rows x 8
            int row = chunk >> 3, c = chunk & 7;
            bf16x8 va = *(const bf16x8*)(A + (size_t)(m0 + row) * 1024 + k0 + c * 8);
            *(bf16x8*)&Ash[row * 64 + ((c ^ (row & 7)) << 3)] = va;
            bf16x8 vb = *(const bf16x8*)(W + (size_t)(n0 + row) * 1024 + k0 + c * 8);
            *(bf16x8*)&Bsh[row * 64 + ((c ^ (row & 7)) << 3)] = vb;
        }
        __syncthreads();
#pragma unroll
        for (int ks = 0; ks < 2; ++ks) {
            bf16x8 af[4], bfv[4];
#pragma unroll
            for (int mi = 0; mi < 4; ++mi) {
                int row = wm * 64 + mi * 16 + (lane & 15);
                int c = ks * 4 + (lane >> 4);
                af[mi] = *(const bf16x8*)&Ash[row * 64 + ((c ^ (row & 7)) << 3)];
            }
#pragma unroll
            for (int ni = 0; ni < 4; ++ni) {
                int row = wn * 64 + ni * 16 + (lane & 15);
                int c = ks * 4 + (lane >> 4);
                bfv[ni] = *(const bf16x8*)&Bsh[row * 64 + ((c ^ (row & 7)) << 3)];
            }
#pragma unroll
            for (int mi = 0; mi < 4; ++mi)
#pragma unroll
                for (int ni = 0; ni < 4; ++ni)
                    acc[mi][ni] = __builtin_amdgcn_mfma_f32_16x16x32_bf16(
                        af[mi], bfv[ni], acc[mi][ni], 0, 0, 0);
        }
    }

    int mbase = m0 + wm * 64, nbase = n0 + wn * 64;

    if (mode == 0 || mode == 1) {
        unsigned short* dst = (mode == 0) ? q_hm : k_hm;
#pragma unroll
        for (int mi = 0; mi < 4; ++mi)
#pragma unroll
            for (int ni = 0; ni < 4; ++ni)
#pragma unroll
                for (int r = 0; r < 4; ++r) {
                    int m = mbase + mi * 16 + ((lane >> 4) << 2) + r;
                    int n = nbase + ni * 16 + (lane & 15);
                    int s = m & 2047, b = m >> 11, h = n >> 6, d = n & 63, j = d & 31;
                    float v  = acc[mi][ni][r];
                    float v2 = acc[mi][ni ^ 2][r];     // partner d +/- 32 (same lane)
                    float cs = cosT[s * 32 + j], sn = sinT[s * 32 + j];
                    float rot = (d < 32) ? -v2 : v2;
                    float o = v * cs + rot * sn;
                    dst[((size_t)(b * 16 + h) * 2048 + s) * 64 + d] = f2bf(o);
                }
    } else if (mode == 2) {
#pragma unroll
        for (int mi = 0; mi < 4; ++mi)
#pragma unroll
            for (int ni = 0; ni < 4; ++ni)
#pragma unroll
                for (int r = 0; r < 4; ++r) {
                    int m = mbase + mi * 16 + ((lane >> 4) << 2) + r;
                    int n = nbase + ni * 16 + (lane & 15);
                    int s = m & 2047, b = m >> 11, h = n >> 6, d = n & 63;
                    v_hm[((size_t)(b * 16 + h) * 2048 + s) * 64 + d] = f2bf(acc[mi][ni][r]);
                }
    } else if (mode == 3) {
#pragma unroll
        for (int mi = 0; mi < 4; ++mi)
#pragma unroll
            for (int ni = 0; ni < 4; ++ni)
#pragma unroll
                for (int r = 0; r < 4; ++r) {
                    int m = mbase + mi * 16 + ((lane >> 4) << 2) + r;
                    int n = nbase + ni * 16 + (lane & 15);
                    float v = acc[mi][ni][r];
                    gate[(size_t)m * 1024 + n] = v / (1.0f + expf(-v));   // silu, f32
                }
    } else {
#pragma unroll
        for (int mi = 0; mi < 4; ++mi)
#pragma unroll
            for (int ni = 0; ni < 4; ++ni)
#pragma unroll
                for (int r = 0; r < 4; ++r) {
                    int m = mbase + mi * 16 + ((lane >> 4) << 2) + r;
                    int n = nbase + ni * 16 + (lane & 15);
                    outf[(size_t)m * 1024 + n] = acc[mi][ni][r];          // f32 output
                }
    }
}

// ---------------------------------------------------------------------------
// Retention + GroupNorm + gate.  Block = one (b,h) x 64 q-rows; 4 waves x 16 rows.
// For each 32-wide t-tile: QK^T (MFMA), decay*mask*scale, scores->LDS->PV MFMA.
// Epilogue: per-row mean/var over Dh=64 (16-lane shuffle reduce), gn, *gate -> a2.
// ---------------------------------------------------------------------------
__launch_bounds__(256, 2)
__global__ void retention_kernel(const unsigned short* __restrict__ qh,
                                 const unsigned short* __restrict__ kh,
                                 const unsigned short* __restrict__ vh,
                                 const float* __restrict__ gn_w, const float* __restrict__ gn_b,
                                 const float* __restrict__ gate,
                                 unsigned short* __restrict__ a2) {
    __shared__ __align__(16) unsigned short Vsh[32 * 64];
    __shared__ __align__(16) unsigned short Ssh[4][16 * 40];  // 80B rows (bank-spread)

    int tid = threadIdx.x, lane = tid & 63, wid = tid >> 6;
    int bh = blockIdx.x, qt = blockIdx.y;
    int b = bh >> 4, h = bh & 15;
    float lg2g = log2f(1.0f - exp2f(-5.0f - (float)h));
    int srow = qt * 64 + wid * 16;

    // Q fragments (held for the whole block)
    bf16x8 aq[2];
    {
        int qr = srow + (lane & 15);
        const unsigned short* qp = qh + ((size_t)bh * 2048 + qr) * 64 + ((lane >> 4) << 3);
        aq[0] = *(const bf16x8*)(qp);
        aq[1] = *(const bf16x8*)(qp + 32);
    }

    f32x4 o[4];
#pragma unroll
    for (int i = 0; i < 4; ++i)
#pragma unroll
        for (int r = 0; r < 4; ++r) o[i][r] = 0.0f;

    int nkt = (qt + 1) * 2;  // 32-wide t-tiles covering t <= qt*64+63
    for (int kt = 0; kt < nkt; ++kt) {
        int t0 = kt * 32;
        __syncthreads();
        {   // stage V tile [32][64] (swizzled 16B chunks: c ^= t>>3)
            int vt = tid >> 3, c = tid & 7;
            bf16x8 v = *(const bf16x8*)(vh + ((size_t)bh * 2048 + t0 + vt) * 64 + c * 8);
            *(bf16x8*)&Vsh[vt * 64 + ((c ^ (vt >> 3)) << 3)] = v;
        }
        __syncthreads();

        // QK^T : 2 t-blocks x 2 k-steps
        f32x4 sc[2];
#pragma unroll
        for (int tb = 0; tb < 2; ++tb)
#pragma unroll
            for (int r = 0; r < 4; ++r) sc[tb][r] = 0.0f;
#pragma unroll
        for (int tb = 0; tb < 2; ++tb)
#pragma unroll
            for (int ks = 0; ks < 2; ++ks) {
                bf16x8 bk = *(const bf16x8*)(kh + ((size_t)bh * 2048 + t0 + tb * 16 + (lane & 15)) * 64
                                             + ks * 32 + ((lane >> 4) << 3));
                sc[tb] = __builtin_amdgcn_mfma_f32_16x16x32_bf16(aq[ks], bk, sc[tb], 0, 0, 0);
            }

        // decay * causal mask * scaling -> bf16 -> per-wave LDS scores
#pragma unroll
        for (int tb = 0; tb < 2; ++tb)
#pragma unroll
            for (int r = 0; r < 4; ++r) {
                int s_abs = srow + ((lane >> 4) << 2) + r;
                int t_abs = t0 + tb * 16 + (lane & 15);
                int dlt = s_abs - t_abs;
                float val = 0.0f;
                if (dlt >= 0) val = sc[tb][r] * 0.125f * exp2f((float)dlt * lg2g);
                Ssh[wid][(((lane >> 4) << 2) + r) * 40 + tb * 16 + (lane & 15)] = f2bf(val);
            }

        // PV: A = scores [16q x 32t], B = V [32t x 64d]
        bf16x8 sf = *(const bf16x8*)&Ssh[wid][(lane & 15) * 40 + ((lane >> 4) << 3)];
#pragma unroll
        for (int db = 0; db < 4; ++db) {
            bf16x8 bv;
            int g = lane >> 4, dcol = lane & 15;
#pragma unroll
            for (int j = 0; j < 8; ++j) {
                int t = g * 8 + j;
                int d = db * 16 + dcol;
                bv[j] = (short)Vsh[t * 64 + (((d >> 3) ^ g) << 3) + (d & 7)];
            }
            o[db] = __builtin_amdgcn_mfma_f32_16x16x32_bf16(sf, bv, o[db], 0, 0, 0);
        }
    }

    // GroupNorm over Dh=64 per row, then *gate, store bf16 row-major [4096][1024]
    float mean[4], rstd[4];
#pragma unroll
    for (int r = 0; r < 4; ++r) {
        float s1 = o[0][r] + o[1][r] + o[2][r] + o[3][r];
        float s2 = o[0][r] * o[0][r] + o[1][r] * o[1][r] + o[2][r] * o[2][r] + o[3][r] * o[3][r];
#pragma unroll
        for (int m = 1; m < 16; m <<= 1) {
            s1 += __shfl_xor(s1, m);
            s2 += __shfl_xor(s2, m);
        }
        float mu = s1 * 0.015625f;
        mean[r] = mu;
        float var = s2 * 0.015625f - mu * mu;
        rstd[r] = rsqrtf(var + 1e-5f);
    }
#pragma unroll
    for (int db = 0; db < 4; ++db) {
        int d = db * 16 + (lane & 15);
        float gw = gn_w[h * 64 + d];
        float gb = gn_b[h * 64 + d];
#pragma unroll
        for (int r = 0; r < 4; ++r) {
            int s_abs = srow + ((lane >> 4) << 2) + r;
            size_t gi = ((size_t)(b * 2048 + s_abs)) * 1024 + h * 64 + d;
            float val = (o[db][r] - mean[r]) * rstd[r] * gw + gb;
            val *= gate[gi];
            a2[gi] = f2bf(val);
        }
    }
}

// ---------------------------------------------------------------------------
extern "C" void kernel_launch(void* const* d_in, const int* in_sizes, int n_in,
                              void* d_out, int out_size, void* d_ws, size_t ws_size,
                              hipStream_t stream) {
    const float* x    = (const float*)d_in[0];
    const float* Wq   = (const float*)d_in[1];
    const float* Wk   = (const float*)d_in[2];
    const float* Wv   = (const float*)d_in[3];
    const float* Wg   = (const float*)d_in[4];
    const float* Wo   = (const float*)d_in[5];
    const float* gn_w = (const float*)d_in[6];
    const float* gn_b = (const float*)d_in[7];

    // workspace layout; total ~70 MB
    unsigned short* xb   = (unsigned short*)d_ws;          // 4096*1024 bf16
    unsigned short* wqb  = xb  + 4194304;                  // 1024*1024 bf16 each
    unsigned short* wkb  = wqb + 1048576;
    unsigned short* wvb  = wkb + 1048576;
    unsigned short* wgb  = wvb + 1048576;
    unsigned short* wob  = wgb + 1048576;
    float*          cosT = (float*)(wob + 1048576);        // 2048*32 f32
    float*          sinT = cosT + 65536;
    unsigned short* q_hm = (unsigned short*)(sinT + 65536);// 4096*1024 bf16 head-major
    unsigned short* k_hm = q_hm + 4194304;
    unsigned short* v_hm = k_hm + 4194304;
    unsigned short* a2   = v_hm + 4194304;                 // 4096*1024 bf16 row-major
    float*          gate = (float*)(a2 + 4194304);         // 4096*1024 f32 row-major

    float* outf = (float*)d_out;

    convert_kernel<<<dim3(2048), dim3(256), 0, stream>>>(x, Wq, Wk, Wv, Wg, Wo, xb);
    rope_tables<<<dim3(256), dim3(256), 0, stream>>>(cosT, sinT);
    gemm_fused<<<dim3(8, 32, 4), dim3(256), 0, stream>>>(
        xb, a2, wqb, wkb, wvb, wgb, wob, cosT, sinT,
        q_hm, k_hm, v_hm, gate, outf, 0);
    retention_kernel<<<dim3(32, 32), dim3(256), 0, stream>>>(
        q_hm, k_hm, v_hm, gn_w, gn_b, gate, a2);
    gemm_fused<<<dim3(8, 32, 1), dim3(256), 0, stream>>>(
        xb, a2, wqb, wkb, wvb, wgb, wob, cosT, sinT,
        q_hm, k_hm, v_hm, gate, outf, 4);
}

// Round 3
// 201.405 us; speedup vs baseline: 1.0202x; 1.0202x over previous
//
#include <hip/hip_runtime.h>
#include <cstdint>
#include <cstddef>

// ---------------------------------------------------------------------------
// RetentionLayer: x->(QKVG proj + RoPE/SiLU) -> causal decay retention ->
// GroupNorm(64)*gate -> @ Wo^T.   B=2 S=2048 D=1024 H=16 Dh=64.
// GEMM-shaped work in bf16 MFMA (16x16x32), f32 accum. OUTPUT IS F32.
// Retention: swapped QK^T (S^T in regs), per-wave LDS score repack (no
// barriers), V consumed directly from global in transposed [bh][d][t] layout.
// ---------------------------------------------------------------------------

typedef __attribute__((ext_vector_type(4))) float  f32x4;
typedef __attribute__((ext_vector_type(8))) short  bf16x8;
typedef __attribute__((ext_vector_type(2))) unsigned int u32x2;

#define S_LEN   2048
#define NHEADS  16
#define DMODEL  1024
#define MROWS   4096   // B*S

__device__ __forceinline__ unsigned short f2bf(float f) {
    unsigned u = __float_as_uint(f);
    u += 0x7fffu + ((u >> 16) & 1u);   // RNE
    return (unsigned short)(u >> 16);
}

__device__ __forceinline__ unsigned cvt_pk_bf16(float lo, float hi) {
    unsigned r;
    asm("v_cvt_pk_bf16_f32 %0, %1, %2" : "=v"(r) : "v"(lo), "v"(hi));
    return r;
}

// ---------------------------------------------------------------------------
// f32 -> bf16 convert: x (4096x1024) then Wq,Wk,Wv,Wg,Wo (1024x1024 each)
// ---------------------------------------------------------------------------
__global__ void convert_kernel(const float* __restrict__ x,
                               const float* __restrict__ wq, const float* __restrict__ wk,
                               const float* __restrict__ wv, const float* __restrict__ wg,
                               const float* __restrict__ wo,
                               unsigned short* __restrict__ dst) {
    const size_t total = 4194304u + 5u * 1048576u;  // 9437184
    for (size_t i = (size_t)blockIdx.x * blockDim.x + threadIdx.x;
         i * 4 < total; i += (size_t)gridDim.x * blockDim.x) {
        size_t e = i * 4;
        const float* src; size_t off;
        if (e < 4194304u) { src = x; off = e; }
        else {
            size_t r = e - 4194304u;
            int w = (int)(r >> 20); off = r & 1048575u;
            src = (w == 0) ? wq : (w == 1) ? wk : (w == 2) ? wv : (w == 3) ? wg : wo;
        }
        f32x4 v = *(const f32x4*)(src + off);
        unsigned short o0 = f2bf(v[0]), o1 = f2bf(v[1]), o2 = f2bf(v[2]), o3 = f2bf(v[3]);
        unsigned long long pack = (unsigned long long)o0 | ((unsigned long long)o1 << 16)
                                | ((unsigned long long)o2 << 32) | ((unsigned long long)o3 << 48);
        *(unsigned long long*)(dst + e) = pack;
    }
}

// ---------------------------------------------------------------------------
// RoPE tables: cos/sin[s][j], j=0..31, inv_freq = 10000^(-j/32)
// ---------------------------------------------------------------------------
__global__ void rope_tables(float* __restrict__ cosT, float* __restrict__ sinT) {
    int i = blockIdx.x * blockDim.x + threadIdx.x;
    if (i >= S_LEN * 32) return;
    int s = i >> 5, j = i & 31;
    float inv = exp2f(-(float)j * (13.287712379549449f / 32.0f)); // log2(10000)
    float ang = (float)s * inv;
    cosT[i] = cosf(ang);
    sinT[i] = sinf(ang);
}

// ---------------------------------------------------------------------------
// GEMM: C[4096,1024] = A[4096,1024] @ W[1024,1024]^T  (both bf16, K-major rows)
// 128x128 tile, BK=64, 4 waves (2x2 of 64x64). XOR-swizzled LDS (chunk^row&7).
// mode 0: ->q_hm (+RoPE)   1: ->k_hm (+RoPE)
// mode 2: ->vT transposed [bh][d][t]  (computes C^T via swapped mfma operands)
// mode 3: ->gate f32 (SiLU)           4: A=a2, W=Wo -> d_out (f32)
// head-major (hm) layout: [(b*16+h)*2048 + s]*64 + d
// ---------------------------------------------------------------------------
__launch_bounds__(256, 2)
__global__ void gemm_fused(const unsigned short* __restrict__ A_x,
                           const unsigned short* __restrict__ A_a2,
                           const unsigned short* __restrict__ Wq, const unsigned short* __restrict__ Wk,
                           const unsigned short* __restrict__ Wv, const unsigned short* __restrict__ Wg,
                           const unsigned short* __restrict__ Wo,
                           const float* __restrict__ cosT, const float* __restrict__ sinT,
                           unsigned short* __restrict__ q_hm, unsigned short* __restrict__ k_hm,
                           unsigned short* __restrict__ vT, float* __restrict__ gate,
                           float* __restrict__ outf,
                           int mode_base) {
    int mode = mode_base + blockIdx.z;
    const unsigned short* A = (mode == 4) ? A_a2 : A_x;
    const unsigned short* W = (mode == 0) ? Wq : (mode == 1) ? Wk :
                              (mode == 2) ? Wv : (mode == 3) ? Wg : Wo;

    __shared__ __align__(16) unsigned short Ash[128 * 64];
    __shared__ __align__(16) unsigned short Bsh[128 * 64];

    int tid = threadIdx.x;
    int lane = tid & 63, wid = tid >> 6;
    int wm = wid >> 1, wn = wid & 1;
    int m0 = blockIdx.y * 128, n0 = blockIdx.x * 128;

    f32x4 acc[4][4];
#pragma unroll
    for (int i = 0; i < 4; ++i)
#pragma unroll
        for (int j = 0; j < 4; ++j)
#pragma unroll
            for (int r = 0; r < 4; ++r) acc[i][j][r] = 0.0f;

    for (int k0 = 0; k0 < 1024; k0 += 64) {
        __syncthreads();
#pragma unroll
        for (int t = 0; t < 4; ++t) {
            int chunk = tid + t * 256;           // 1024 chunks = 128 rows x 8
            int row = chunk >> 3, c = chunk & 7;
            bf16x8 va = *(const bf16x8*)(A + (size_t)(m0 + row) * 1024 + k0 + c * 8);
            *(bf16x8*)&Ash[row * 64 + ((c ^ (row & 7)) << 3)] = va;
            bf16x8 vb = *(const bf16x8*)(W + (size_t)(n0 + row) * 1024 + k0 + c * 8);
            *(bf16x8*)&Bsh[row * 64 + ((c ^ (row & 7)) << 3)] = vb;
        }
        __syncthreads();
#pragma unroll
        for (int ks = 0; ks < 2; ++ks) {
            bf16x8 af[4], bfv[4];
#pragma unroll
            for (int mi = 0; mi < 4; ++mi) {
                int row = wm * 64 + mi * 16 + (lane & 15);
                int c = ks * 4 + (lane >> 4);
                af[mi] = *(const bf16x8*)&Ash[row * 64 + ((c ^ (row & 7)) << 3)];
            }
#pragma unroll
            for (int ni = 0; ni < 4; ++ni) {
                int row = wn * 64 + ni * 16 + (lane & 15);
                int c = ks * 4 + (lane >> 4);
                bfv[ni] = *(const bf16x8*)&Bsh[row * 64 + ((c ^ (row & 7)) << 3)];
            }
            if (mode == 2) {   // C^T: A-operand = W (rows=n), B-operand = x (cols=m)
#pragma unroll
                for (int mi = 0; mi < 4; ++mi)
#pragma unroll
                    for (int ni = 0; ni < 4; ++ni)
                        acc[mi][ni] = __builtin_amdgcn_mfma_f32_16x16x32_bf16(
                            bfv[ni], af[mi], acc[mi][ni], 0, 0, 0);
            } else {
#pragma unroll
                for (int mi = 0; mi < 4; ++mi)
#pragma unroll
                    for (int ni = 0; ni < 4; ++ni)
                        acc[mi][ni] = __builtin_amdgcn_mfma_f32_16x16x32_bf16(
                            af[mi], bfv[ni], acc[mi][ni], 0, 0, 0);
            }
        }
    }

    int mbase = m0 + wm * 64, nbase = n0 + wn * 64;

    if (mode == 0 || mode == 1) {
        unsigned short* dst = (mode == 0) ? q_hm : k_hm;
#pragma unroll
        for (int mi = 0; mi < 4; ++mi)
#pragma unroll
            for (int ni = 0; ni < 4; ++ni)
#pragma unroll
                for (int r = 0; r < 4; ++r) {
                    int m = mbase + mi * 16 + ((lane >> 4) << 2) + r;
                    int n = nbase + ni * 16 + (lane & 15);
                    int s = m & 2047, b = m >> 11, h = n >> 6, d = n & 63, j = d & 31;
                    float v  = acc[mi][ni][r];
                    float v2 = acc[mi][ni ^ 2][r];     // partner d +/- 32 (same lane)
                    float cs = cosT[s * 32 + j], sn = sinT[s * 32 + j];
                    float rot = (d < 32) ? -v2 : v2;
                    float o = v * cs + rot * sn;
                    dst[((size_t)(b * 16 + h) * 2048 + s) * 64 + d] = f2bf(o);
                }
    } else if (mode == 2) {   // acc = C^T fragments: row=n(out-feature), col=m(token)
#pragma unroll
        for (int mi = 0; mi < 4; ++mi)
#pragma unroll
            for (int ni = 0; ni < 4; ++ni)
#pragma unroll
                for (int r = 0; r < 4; ++r) {
                    int n = nbase + ni * 16 + ((lane >> 4) << 2) + r;
                    int m = mbase + mi * 16 + (lane & 15);
                    int b = m >> 11, s = m & 2047, h = n >> 6, d = n & 63;
                    vT[((size_t)((b * 16 + h) * 64 + d)) * 2048 + s] = f2bf(acc[mi][ni][r]);
                }
    } else if (mode == 3) {
#pragma unroll
        for (int mi = 0; mi < 4; ++mi)
#pragma unroll
            for (int ni = 0; ni < 4; ++ni)
#pragma unroll
                for (int r = 0; r < 4; ++r) {
                    int m = mbase + mi * 16 + ((lane >> 4) << 2) + r;
                    int n = nbase + ni * 16 + (lane & 15);
                    float v = acc[mi][ni][r];
                    gate[(size_t)m * 1024 + n] = v / (1.0f + expf(-v));   // silu, f32
                }
    } else {
#pragma unroll
        for (int mi = 0; mi < 4; ++mi)
#pragma unroll
            for (int ni = 0; ni < 4; ++ni)
#pragma unroll
                for (int r = 0; r < 4; ++r) {
                    int m = mbase + mi * 16 + ((lane >> 4) << 2) + r;
                    int n = nbase + ni * 16 + (lane & 15);
                    outf[(size_t)m * 1024 + n] = acc[mi][ni][r];          // f32 output
                }
    }
}

// ---------------------------------------------------------------------------
// Retention + GroupNorm + gate.  512 blocks; block = (bh, z) handles q-strips
// qt=z and qt=31-z (uniform 66 tiles). 4 waves x 16 q-rows. No __syncthreads:
// swapped QK^T -> S^T regs -> per-wave LDS (b64 writes / b128 read) -> PV with
// V direct-from-global (transposed layout). XCD-bijective bh grouping.
// ---------------------------------------------------------------------------
__launch_bounds__(256, 2)
__global__ void retention_kernel(const unsigned short* __restrict__ qh,
                                 const unsigned short* __restrict__ kh,
                                 const unsigned short* __restrict__ vT,
                                 const float* __restrict__ gn_w, const float* __restrict__ gn_b,
                                 const float* __restrict__ gate,
                                 unsigned short* __restrict__ a2) {
    __shared__ __align__(16) unsigned short Ssh[4][16 * 40];  // per-wave, 80B row pitch

    int tid = threadIdx.x, lane = tid & 63, wid = tid >> 6;
    int flat = blockIdx.y * 32 + blockIdx.x;        // 512 blocks
    int xcd = flat & 7, slot = flat >> 3;           // group 4 bh per XCD (L2 locality)
    int bh = xcd * 4 + (slot >> 4);
    int z  = slot & 15;
    int b = bh >> 4, h = bh & 15;

    float lg2g = log2f(1.0f - exp2f(-5.0f - (float)h));
    float gmr1 = exp2f(-lg2g);                      // gamma^-1
    float gmr2 = gmr1 * gmr1, gmr3 = gmr2 * gmr1;

    int q_lane = lane & 15;
    int g4 = (lane >> 4) << 2, g8 = (lane >> 4) << 3;

    const unsigned short* kbase = kh + (size_t)bh * 2048 * 64;
    const unsigned short* vbase = vT + (size_t)bh * 64 * 2048;
    unsigned short* ssw = &Ssh[wid][0];

    for (int pass = 0; pass < 2; ++pass) {
        int qt = pass ? (31 - z) : z;
        int srow = qt * 64 + wid * 16;
        int s_abs = srow + q_lane;

        bf16x8 aq0, aq1;
        {
            const unsigned short* qp = qh + ((size_t)bh * 2048 + s_abs) * 64 + g8;
            aq0 = *(const bf16x8*)(qp);
            aq1 = *(const bf16x8*)(qp + 32);
        }
        float gq8 = 0.125f * exp2f((float)s_abs * lg2g);   // scaling * gamma^s

        f32x4 o[4];
#pragma unroll
        for (int i = 0; i < 4; ++i)
#pragma unroll
            for (int r = 0; r < 4; ++r) o[i][r] = 0.0f;

        int nkt = (qt + 1) * 2;
        for (int kt = 0; kt < nkt; ++kt) {
            int t0 = kt * 32;
            if (t0 > srow + 15) break;   // fully-masked for this wave's rows

            // --- QK^T swapped: S^T[t][q] = sum_d K[t][d] Q[q][d]
            f32x4 sc[2];
#pragma unroll
            for (int tb = 0; tb < 2; ++tb)
#pragma unroll
                for (int r = 0; r < 4; ++r) sc[tb][r] = 0.0f;
#pragma unroll
            for (int tb = 0; tb < 2; ++tb) {
                const unsigned short* kp = kbase + (size_t)(t0 + tb * 16 + q_lane) * 64 + g8;
                bf16x8 bk0 = *(const bf16x8*)(kp);
                bf16x8 bk1 = *(const bf16x8*)(kp + 32);
                sc[tb] = __builtin_amdgcn_mfma_f32_16x16x32_bf16(bk0, aq0, sc[tb], 0, 0, 0);
                sc[tb] = __builtin_amdgcn_mfma_f32_16x16x32_bf16(bk1, aq1, sc[tb], 0, 0, 0);
            }

            // --- decay * mask * scale -> bf16 pack -> per-wave LDS (b64 writes)
#pragma unroll
            for (int tb = 0; tb < 2; ++tb) {
                int tbase = t0 + tb * 16 + g4;      // lane's first t (reg r adds +r)
                float d0 = gq8 * exp2f((float)(-tbase) * lg2g);
                float v0 = (s_abs - tbase     >= 0) ? sc[tb][0] * d0        : 0.0f;
                float v1 = (s_abs - tbase - 1 >= 0) ? sc[tb][1] * d0 * gmr1 : 0.0f;
                float v2 = (s_abs - tbase - 2 >= 0) ? sc[tb][2] * d0 * gmr2 : 0.0f;
                float v3 = (s_abs - tbase - 3 >= 0) ? sc[tb][3] * d0 * gmr3 : 0.0f;
                u32x2 w;
                w[0] = cvt_pk_bf16(v0, v1);
                w[1] = cvt_pk_bf16(v2, v3);
                *(u32x2*)&ssw[q_lane * 40 + tb * 16 + g4] = w;
            }

            // --- PV: A = scores [16q x 32t] (b128 read), B = V^T direct global
            bf16x8 sf = *(const bf16x8*)&ssw[q_lane * 40 + g8];
#pragma unroll
            for (int db = 0; db < 4; ++db) {
                bf16x8 bv = *(const bf16x8*)(vbase + (size_t)(db * 16 + q_lane) * 2048 + t0 + g8);
                o[db] = __builtin_amdgcn_mfma_f32_16x16x32_bf16(sf, bv, o[db], 0, 0, 0);
            }
        }

        // --- GroupNorm over Dh=64 per row, *gate, store bf16 [4096][1024]
        float mean[4], rstd[4];
#pragma unroll
        for (int r = 0; r < 4; ++r) {
            float s1 = o[0][r] + o[1][r] + o[2][r] + o[3][r];
            float s2 = o[0][r] * o[0][r] + o[1][r] * o[1][r] + o[2][r] * o[2][r] + o[3][r] * o[3][r];
#pragma unroll
            for (int m = 1; m < 16; m <<= 1) {
                s1 += __shfl_xor(s1, m);
                s2 += __shfl_xor(s2, m);
            }
            float mu = s1 * 0.015625f;
            mean[r] = mu;
            float var = s2 * 0.015625f - mu * mu;
            rstd[r] = rsqrtf(var + 1e-5f);
        }
#pragma unroll
        for (int db = 0; db < 4; ++db) {
            int d = db * 16 + q_lane;
            float gw = gn_w[h * 64 + d];
            float gb = gn_b[h * 64 + d];
#pragma unroll
            for (int r = 0; r < 4; ++r) {
                int s_out = srow + g4 + r;
                size_t gi = ((size_t)(b * 2048 + s_out)) * 1024 + h * 64 + d;
                float val = (o[db][r] - mean[r]) * rstd[r] * gw + gb;
                val *= gate[gi];
                a2[gi] = f2bf(val);
            }
        }
    }
}

// ---------------------------------------------------------------------------
extern "C" void kernel_launch(void* const* d_in, const int* in_sizes, int n_in,
                              void* d_out, int out_size, void* d_ws, size_t ws_size,
                              hipStream_t stream) {
    const float* x    = (const float*)d_in[0];
    const float* Wq   = (const float*)d_in[1];
    const float* Wk   = (const float*)d_in[2];
    const float* Wv   = (const float*)d_in[3];
    const float* Wg   = (const float*)d_in[4];
    const float* Wo   = (const float*)d_in[5];
    const float* gn_w = (const float*)d_in[6];
    const float* gn_b = (const float*)d_in[7];

    // workspace layout; total ~70 MB
    unsigned short* xb   = (unsigned short*)d_ws;          // 4096*1024 bf16
    unsigned short* wqb  = xb  + 4194304;                  // 1024*1024 bf16 each
    unsigned short* wkb  = wqb + 1048576;
    unsigned short* wvb  = wkb + 1048576;
    unsigned short* wgb  = wvb + 1048576;
    unsigned short* wob  = wgb + 1048576;
    float*          cosT = (float*)(wob + 1048576);        // 2048*32 f32
    float*          sinT = cosT + 65536;
    unsigned short* q_hm = (unsigned short*)(sinT + 65536);// 4096*1024 bf16 head-major
    unsigned short* k_hm = q_hm + 4194304;
    unsigned short* vTb  = k_hm + 4194304;                 // 4096*1024 bf16 [bh][d][t]
    unsigned short* a2   = vTb + 4194304;                  // 4096*1024 bf16 row-major
    float*          gate = (float*)(a2 + 4194304);         // 4096*1024 f32 row-major

    float* outf = (float*)d_out;

    convert_kernel<<<dim3(2048), dim3(256), 0, stream>>>(x, Wq, Wk, Wv, Wg, Wo, xb);
    rope_tables<<<dim3(256), dim3(256), 0, stream>>>(cosT, sinT);
    gemm_fused<<<dim3(8, 32, 4), dim3(256), 0, stream>>>(
        xb, a2, wqb, wkb, wvb, wgb, wob, cosT, sinT,
        q_hm, k_hm, vTb, gate, outf, 0);
    retention_kernel<<<dim3(32, 16), dim3(256), 0, stream>>>(
        q_hm, k_hm, vTb, gn_w, gn_b, gate, a2);
    gemm_fused<<<dim3(8, 32, 1), dim3(256), 0, stream>>>(
        xb, a2, wqb, wkb, wvb, wgb, wob, cosT, sinT,
        q_hm, k_hm, vTb, gate, outf, 4);
}